// Round 1
// baseline (244.480 us; speedup 1.0000x reference)
//
#include <hip/hip_runtime.h>
#include <hip/hip_bf16.h>
#include <cstdint>

typedef unsigned short u16;
typedef __attribute__((ext_vector_type(8))) short short8;
typedef __attribute__((ext_vector_type(4))) float f32x4;
typedef __attribute__((ext_vector_type(4))) unsigned short us4;

__device__ __forceinline__ float bf2f(u16 u) {
    union { unsigned int i; float f; } v; v.i = ((unsigned int)u) << 16; return v.f;
}
__device__ __forceinline__ u16 f2bf(float f) {
    union { float f; unsigned int i; } v; v.f = f;
    unsigned int x = v.i;
    unsigned int r = x + 0x7fffu + ((x >> 16) & 1u);  // RNE
    return (u16)(r >> 16);
}

enum { EPI_F32 = 0, EPI_F32_CB = 1, EPI_BF16_RB = 2, EPI_BF16_RS = 3, EPI_BF16_EXP = 4 };

// C[M,N] = A[M,K] * B[N,K]^T  (both K-contiguous), batched via blockIdx.z with
// element strides sA/sB/sC. BK=64, block=256 threads (4 waves, 2x2), m97-style
// global_load_lds(16B) staging, 16x16x32 bf16 MFMA.
template <int BM, int BN, int EPI>
__global__ void __launch_bounds__(256)
gemm_bt(const u16* __restrict__ A, const u16* __restrict__ B, void* __restrict__ Cv,
        int M, int N, int K, long sA, long sB, long sC,
        const float* __restrict__ biasRow, const float* __restrict__ biasCol,
        const float* __restrict__ rowScale, float expScale)
{
    constexpr int BK = 64;
    constexpr int MFRAG = BM / 32;
    constexpr int NFRAG = BN / 32;
    __shared__ alignas(16) u16 As[BM * BK];
    __shared__ alignas(16) u16 Bs[BN * BK];

    const int tid = threadIdx.x;
    const int lane = tid & 63;
    const int quad = lane >> 4;
    const int l15 = lane & 15;
    const int w = tid >> 6;
    const int wm = w >> 1, wn = w & 1;
    const int z = blockIdx.z;
    const int m0 = blockIdx.y * BM;
    const int n0 = blockIdx.x * BN;

    const u16* Ab = A + (long)z * sA + (long)m0 * K;
    const u16* Bb = B + (long)z * sB + (long)n0 * K;

    const int r8 = tid >> 3;          // 0..31: row within 32-row staging round
    const int c8 = (tid & 7) * 8;     // k-offset in elements (16B chunks)

    f32x4 acc[MFRAG][NFRAG] = {};

    for (int k0 = 0; k0 < K; k0 += BK) {
#pragma unroll
        for (int j = 0; j < BM / 32; ++j) {
            const u16* gp = Ab + (long)(j * 32 + r8) * K + (k0 + c8);
            __builtin_amdgcn_global_load_lds(
                (const __attribute__((address_space(1))) void*)gp,
                (__attribute__((address_space(3))) void*)(&As[(j * 32 + r8) * BK + c8]),
                16, 0, 0);
        }
#pragma unroll
        for (int j = 0; j < BN / 32; ++j) {
            const u16* gp = Bb + (long)(j * 32 + r8) * K + (k0 + c8);
            __builtin_amdgcn_global_load_lds(
                (const __attribute__((address_space(1))) void*)gp,
                (__attribute__((address_space(3))) void*)(&Bs[(j * 32 + r8) * BK + c8]),
                16, 0, 0);
        }
        __syncthreads();
#pragma unroll
        for (int ks = 0; ks < 2; ++ks) {
            short8 af[MFRAG], bfr[NFRAG];
#pragma unroll
            for (int i = 0; i < MFRAG; ++i)
                af[i] = *(const short8*)&As[(wm * (BM / 2) + i * 16 + l15) * BK + ks * 32 + quad * 8];
#pragma unroll
            for (int i = 0; i < NFRAG; ++i)
                bfr[i] = *(const short8*)&Bs[(wn * (BN / 2) + i * 16 + l15) * BK + ks * 32 + quad * 8];
#pragma unroll
            for (int i = 0; i < MFRAG; ++i)
#pragma unroll
                for (int jn = 0; jn < NFRAG; ++jn)
                    acc[i][jn] = __builtin_amdgcn_mfma_f32_16x16x32_bf16(af[i], bfr[jn], acc[i][jn], 0, 0, 0);
        }
        __syncthreads();
    }

    // Epilogue: C/D layout col=lane&15, row=quad*4+reg (guide §3, m89/m91 verified)
#pragma unroll
    for (int i = 0; i < MFRAG; ++i) {
        const int mb = m0 + wm * (BM / 2) + i * 16 + quad * 4;
#pragma unroll
        for (int jn = 0; jn < NFRAG; ++jn) {
            const int col = n0 + wn * (BN / 2) + jn * 16 + l15;
#pragma unroll
            for (int r = 0; r < 4; ++r) {
                const int m = mb + r;
                float v = acc[i][jn][r];
                if constexpr (EPI == EPI_F32_CB)  v += biasCol[col];
                if constexpr (EPI == EPI_BF16_RB) v += biasRow[m];
                if constexpr (EPI == EPI_BF16_RS) v *= rowScale[(long)z * M + m];
                if constexpr (EPI == EPI_BF16_EXP) v = exp2f(v * expScale);
                if constexpr (EPI == EPI_F32 || EPI == EPI_F32_CB)
                    ((float*)Cv)[(long)z * sC + (long)m * N + col] = v;
                else
                    ((u16*)Cv)[(long)z * sC + (long)m * N + col] = f2bf(v);
            }
        }
    }
}

__global__ void __launch_bounds__(256)
cast_f2b_k(const float* __restrict__ x, u16* __restrict__ y, long n)
{
    long i = ((long)blockIdx.x * 256 + threadIdx.x) * 4;
    if (i < n) {
        const float4 v = *(const float4*)(x + i);
        us4 o;
        o.x = f2bf(v.x); o.y = f2bf(v.y); o.z = f2bf(v.z); o.w = f2bf(v.w);
        *(us4*)(y + i) = o;
    }
}

// scores [rows,64] f32 -> softmax((s+bl)/8) -> bf16 probs. One row per wave.
__global__ void __launch_bounds__(256)
lm_softmax(const float* __restrict__ S, const float* __restrict__ bl, u16* __restrict__ out)
{
    int row = blockIdx.x * 4 + (threadIdx.x >> 6);
    int lane = threadIdx.x & 63;
    float v = (S[(long)row * 64 + lane] + bl[lane]) * 0.125f;
    float e = __expf(v);  // logits in ~[-0.7,0.7]: no max-subtraction needed
    float s = e;
    for (int o = 32; o; o >>= 1) s += __shfl_xor(s, o, 64);
    out[(long)row * 64 + lane] = f2bf(e / s);
}

// rscale[row] = 1 / sum_k P[row,k]   (P bf16, Lk elems per row)
__global__ void __launch_bounds__(256)
row_recip(const u16* __restrict__ P, float* __restrict__ rs, int Lk)
{
    long row = blockIdx.x;
    const u16* p = P + row * (long)Lk;
    float s = 0.f;
    for (int i = threadIdx.x * 4; i < Lk; i += 256 * 4) {
        us4 v = *(const us4*)(p + i);
        s += bf2f(v.x) + bf2f(v.y) + bf2f(v.z) + bf2f(v.w);
    }
    for (int o = 32; o; o >>= 1) s += __shfl_xor(s, o, 64);
    __shared__ float red[4];
    if ((threadIdx.x & 63) == 0) red[threadIdx.x >> 6] = s;
    __syncthreads();
    if (threadIdx.x == 0) rs[row] = 1.0f / (red[0] + red[1] + red[2] + red[3]);
}

extern "C" void kernel_launch(void* const* d_in, const int* in_sizes, int n_in,
                              void* d_out, int out_size, void* d_ws, size_t ws_size,
                              hipStream_t stream)
{
    const float* query = (const float*)d_in[0];
    const float* key   = (const float*)d_in[1];
    const float* value = (const float*)d_in[2];
    const float* Wv    = (const float*)d_in[3];
    const float* bv    = (const float*)d_in[4];
    const float* Wl    = (const float*)d_in[5];
    const float* bl    = (const float*)d_in[6];
    const float* Wo    = (const float*)d_in[7];
    const float* bo    = (const float*)d_in[8];
    float* out = (float*)d_out;

    // B=2, L=2048, E=1024, H=16, HD=64, M_land=64
    char* ws = (char*)d_ws;
    u16*   qkb    = (u16*)  (ws + 0);          // [8192,1024] bf16 (query rows then key rows)
    u16*   vb     = (u16*)  (ws + 16777216);   // [4096,1024] bf16 value
    u16*   Wvb    = (u16*)  (ws + 25165824);   // [1024,1024]
    u16*   Wlb    = (u16*)  (ws + 27262976);   // [64,1024]
    u16*   Wob    = (u16*)  (ws + 27394048);   // [1024,1024]
    float* scores = (float*)(ws + 29491200);   // [8192,64] f32
    u16*   qlkl   = (u16*)  (ws + 31588352);   // [8192,64] bf16 (ql rows 0..4095, kl 4096..8191)
    u16*   Vt     = (u16*)  (ws + 32636928);   // [2,1024,2048] bf16  (V^T per batch)
    u16*   Pm     = (u16*)  (ws + 41025536);   // [2,2048,2048] bf16  unnormalized exp(S/8)
    float* rsc    = (float*)(ws + 57802752);   // [2,2048] f32 reciprocal row sums
    u16*   O1     = (u16*)  (ws + 57819136);   // [4096,1024] bf16  attn@V

    // 1) casts fp32 -> bf16
    cast_f2b_k<<<dim3(4096), 256, 0, stream>>>(query, qkb,            4194304);
    cast_f2b_k<<<dim3(4096), 256, 0, stream>>>(key,   qkb + 4194304,  4194304);
    cast_f2b_k<<<dim3(4096), 256, 0, stream>>>(value, vb,             4194304);
    cast_f2b_k<<<dim3(1024), 256, 0, stream>>>(Wv,    Wvb,            1048576);
    cast_f2b_k<<<dim3(64),   256, 0, stream>>>(Wl,    Wlb,            65536);
    cast_f2b_k<<<dim3(1024), 256, 0, stream>>>(Wo,    Wob,            1048576);

    // 2) landmark scores: [8192,64] = qkb @ Wl^T   (bias+scale+softmax in next kernel)
    gemm_bt<64, 64, EPI_F32><<<dim3(1, 128, 1), 256, 0, stream>>>(
        qkb, Wlb, scores, 8192, 64, 1024, 0, 0, 0, nullptr, nullptr, nullptr, 0.f);
    // 3) softmax over 64 landmarks
    lm_softmax<<<dim3(2048), 256, 0, stream>>>(scores, bl, qlkl);

    // 4) V^T[z] = Wv @ value[z]^T + bv (row-bias):  [1024,2048] per batch
    gemm_bt<128, 128, EPI_BF16_RB><<<dim3(16, 8, 2), 256, 0, stream>>>(
        Wvb, vb, Vt, 1024, 2048, 1024, 0, 2097152, 2097152, bv, nullptr, nullptr, 0.f);

    // 5) P[z] = exp2( (ql @ kl^T) * 0.125*log2(e) )   [2048,2048] per batch
    gemm_bt<128, 128, EPI_BF16_EXP><<<dim3(16, 16, 2), 256, 0, stream>>>(
        qlkl, qlkl + 4096 * 64, Pm, 2048, 2048, 64,
        2048 * 64, 2048 * 64, (long)2048 * 2048, nullptr, nullptr, nullptr,
        0.18033688011112042f);

    // 6) row reciprocal sums of P
    row_recip<<<dim3(4096), 256, 0, stream>>>(Pm, rsc, 2048);

    // 7) O1[z] = (P[z] @ Vt[z]^T) * rscale[row]   [2048,1024] per batch
    gemm_bt<128, 128, EPI_BF16_RS><<<dim3(8, 16, 2), 256, 0, stream>>>(
        Pm, Vt, O1, 2048, 1024, 2048,
        (long)2048 * 2048, (long)1024 * 2048, (long)2048 * 1024,
        nullptr, nullptr, rsc, 0.f);

    // 8) out = O1 @ Wo^T + bo  (f32, col-bias) -> d_out
    gemm_bt<128, 128, EPI_F32_CB><<<dim3(8, 32, 1), 256, 0, stream>>>(
        O1, Wob, out, 4096, 1024, 1024, 0, 0, 0, nullptr, bo, nullptr, 0.f);
}

// Round 2
// 206.755 us; speedup vs baseline: 1.1825x; 1.1825x over previous
//
#include <hip/hip_runtime.h>
#include <hip/hip_bf16.h>
#include <cstdint>

typedef unsigned short u16;
typedef __attribute__((ext_vector_type(8))) short short8;
typedef __attribute__((ext_vector_type(4))) float f32x4;
typedef __attribute__((ext_vector_type(4))) unsigned short us4;

__device__ __forceinline__ float bf2f(u16 u) {
    union { unsigned int i; float f; } v; v.i = ((unsigned int)u) << 16; return v.f;
}
__device__ __forceinline__ u16 f2bf(float f) {
    union { float f; unsigned int i; } v; v.f = f;
    unsigned int x = v.i;
    unsigned int r = x + 0x7fffu + ((x >> 16) & 1u);  // RNE
    return (u16)(r >> 16);
}

enum { EPI_F32 = 0, EPI_BF16 = 1, EPI_BF16_CB = 2, EPI_EXP_RS = 3, EPI_F32_DIV_CB = 4 };

// C[M,N] = A[M,K] * B[N,K]^T (both K-contiguous), batched via blockIdx.z.
// BK=64, 256 threads (4 waves 2x2), global_load_lds(16B) staging with
// XOR-8 swizzle applied on the GLOBAL address side (LDS lane mapping is fixed:
// base + lane*16), so chunk slot c_l of row r holds global chunk c_l^(r&7).
// Fragment reads invert the XOR -> bank-balanced ds_read_b128 (8 dwords/bank).
template <int BM, int BN, int EPI>
__global__ void __launch_bounds__(256)
gemm_bt(const u16* __restrict__ A, const u16* __restrict__ B, void* __restrict__ Cv,
        int M, int N, int K, long sA, long sB, long sC,
        const float* __restrict__ biasCol, float* __restrict__ rowScale, float expScale)
{
    constexpr int BK = 64;
    constexpr int MFRAG = (BM + 31) / 32;
    constexpr int NFRAG = BN / 32;
    __shared__ alignas(16) u16 As[BM * BK];
    __shared__ alignas(16) u16 Bs[BN * BK];

    const int tid = threadIdx.x;
    const int lane = tid & 63;
    const int quad = lane >> 4;
    const int l15 = lane & 15;
    const int w = tid >> 6;
    const int wm = w >> 1, wn = w & 1;
    const int z = blockIdx.z;
    const int m0 = blockIdx.y * BM;
    const int n0 = blockIdx.x * BN;

    const u16* Ab = A + (long)z * sA + (long)m0 * K;
    const u16* Bb = B + (long)z * sB + (long)n0 * K;

    const int r8 = tid >> 3;                    // 0..31 staging row within round
    const int cl = tid & 7;                     // LDS chunk slot (16B units)
    const int cg = ((cl ^ (r8 & 7)) * 8);       // swizzled global chunk (elements)

    const u16* ap[(BM + 31) / 32];
#pragma unroll
    for (int j = 0; j < (BM + 31) / 32; ++j) ap[j] = Ab + (long)(j * 32 + r8) * K + cg;
    const u16* bp[BN / 32];
#pragma unroll
    for (int j = 0; j < BN / 32; ++j) bp[j] = Bb + (long)(j * 32 + r8) * K + cg;

    f32x4 acc[MFRAG][NFRAG] = {};

    const int sw = l15 & 7;  // row XOR key for fragment reads

    for (int k0 = 0; k0 < K; k0 += BK) {
#pragma unroll
        for (int j = 0; j < (BM + 31) / 32; ++j) {
            __builtin_amdgcn_global_load_lds(
                (const __attribute__((address_space(1))) void*)(ap[j]),
                (__attribute__((address_space(3))) void*)(&As[(j * 32 + r8) * BK + cl * 8]),
                16, 0, 0);
            ap[j] += BK;
        }
#pragma unroll
        for (int j = 0; j < BN / 32; ++j) {
            __builtin_amdgcn_global_load_lds(
                (const __attribute__((address_space(1))) void*)(bp[j]),
                (__attribute__((address_space(3))) void*)(&Bs[(j * 32 + r8) * BK + cl * 8]),
                16, 0, 0);
            bp[j] += BK;
        }
        __syncthreads();
#pragma unroll
        for (int ks = 0; ks < 2; ++ks) {
            short8 af[MFRAG], bfr[NFRAG];
#pragma unroll
            for (int i = 0; i < MFRAG; ++i)
                af[i] = *(const short8*)&As[(wm * (BM / 2) + i * 16 + l15) * BK +
                                            (((ks * 4 + quad) ^ sw) * 8)];
#pragma unroll
            for (int i = 0; i < NFRAG; ++i)
                bfr[i] = *(const short8*)&Bs[(wn * (BN / 2) + i * 16 + l15) * BK +
                                             (((ks * 4 + quad) ^ sw) * 8)];
#pragma unroll
            for (int i = 0; i < MFRAG; ++i)
#pragma unroll
                for (int jn = 0; jn < NFRAG; ++jn)
                    acc[i][jn] = __builtin_amdgcn_mfma_f32_16x16x32_bf16(af[i], bfr[jn], acc[i][jn], 0, 0, 0);
        }
        __syncthreads();
    }

    // Epilogue. C/D layout: col=lane&15, row=quad*4+reg (m89/m91 verified).
#pragma unroll
    for (int i = 0; i < MFRAG; ++i) {
        const int mb = m0 + wm * (BM / 2) + i * 16 + quad * 4;
#pragma unroll
        for (int r = 0; r < 4; ++r) {
            const int m = mb + r;
            float rin = 0.f;
            if constexpr (EPI == EPI_F32_DIV_CB) rin = 1.0f / rowScale[(long)z * M + m];
            float rowsum = 0.f;
#pragma unroll
            for (int jn = 0; jn < NFRAG; ++jn) {
                const int col = n0 + wn * (BN / 2) + jn * 16 + l15;
                float v = acc[i][jn][r];
                if constexpr (EPI == EPI_EXP_RS) { v = exp2f(v * expScale); rowsum += v; }
                if constexpr (EPI == EPI_BF16_CB) v += biasCol[col];
                if constexpr (EPI == EPI_F32_DIV_CB) v = v * rin + biasCol[col];
                if constexpr (EPI == EPI_F32 || EPI == EPI_F32_DIV_CB)
                    ((float*)Cv)[(long)z * sC + (long)m * N + col] = v;
                else
                    ((u16*)Cv)[(long)z * sC + (long)m * N + col] = f2bf(v);
            }
            if constexpr (EPI == EPI_EXP_RS) {
                rowsum += __shfl_xor(rowsum, 1);
                rowsum += __shfl_xor(rowsum, 2);
                rowsum += __shfl_xor(rowsum, 4);
                rowsum += __shfl_xor(rowsum, 8);
                if (l15 == 0) atomicAdd(&rowScale[(long)z * M + m], rowsum);
            }
        }
    }
}

__global__ void __launch_bounds__(256)
cast_f2b_k(const float* __restrict__ x, u16* __restrict__ y, long n)
{
    long i = ((long)blockIdx.x * 256 + threadIdx.x) * 4;
    if (i < n) {
        const float4 v = *(const float4*)(x + i);
        us4 o;
        o.x = f2bf(v.x); o.y = f2bf(v.y); o.z = f2bf(v.z); o.w = f2bf(v.w);
        *(us4*)(y + i) = o;
    }
}

__global__ void __launch_bounds__(256)
cast_qkv(const float* __restrict__ a, const float* __restrict__ b, const float* __restrict__ c,
         u16* __restrict__ oa, u16* __restrict__ ob, u16* __restrict__ oc, long n)
{
    const float* s; u16* d;
    if (blockIdx.y == 0)      { s = a; d = oa; }
    else if (blockIdx.y == 1) { s = b; d = ob; }
    else                      { s = c; d = oc; }
    long i = ((long)blockIdx.x * 256 + threadIdx.x) * 4;
    if (i < n) {
        const float4 v = *(const float4*)(s + i);
        us4 o;
        o.x = f2bf(v.x); o.y = f2bf(v.y); o.z = f2bf(v.z); o.w = f2bf(v.w);
        *(us4*)(d + i) = o;
    }
}

__global__ void __launch_bounds__(256)
cast_ww(const float* __restrict__ a, const float* __restrict__ b,
        u16* __restrict__ oa, u16* __restrict__ ob, long n)
{
    const float* s = blockIdx.y ? b : a;
    u16* d = blockIdx.y ? ob : oa;
    long i = ((long)blockIdx.x * 256 + threadIdx.x) * 4;
    if (i < n) {
        const float4 v = *(const float4*)(s + i);
        us4 o;
        o.x = f2bf(v.x); o.y = f2bf(v.y); o.z = f2bf(v.z); o.w = f2bf(v.w);
        *(us4*)(d + i) = o;
    }
}

// scores [rows,64] f32 -> softmax((s+bl)/8) -> bf16 probs. One row per wave.
__global__ void __launch_bounds__(256)
lm_softmax(const float* __restrict__ S, const float* __restrict__ bl, u16* __restrict__ out)
{
    int row = blockIdx.x * 4 + (threadIdx.x >> 6);
    int lane = threadIdx.x & 63;
    float v = (S[(long)row * 64 + lane] + bl[lane]) * 0.125f;
    float e = __expf(v);  // logits in ~[-0.7,0.7]: no max-subtraction needed
    float s = e;
    for (int o = 32; o; o >>= 1) s += __shfl_xor(s, o, 64);
    out[(long)row * 64 + lane] = f2bf(e / s);
}

__global__ void __launch_bounds__(256)
zero_f32(float* __restrict__ p, int n)
{
    int i = blockIdx.x * 256 + threadIdx.x;
    if (i < n) p[i] = 0.f;
}

extern "C" void kernel_launch(void* const* d_in, const int* in_sizes, int n_in,
                              void* d_out, int out_size, void* d_ws, size_t ws_size,
                              hipStream_t stream)
{
    const float* query = (const float*)d_in[0];
    const float* key   = (const float*)d_in[1];
    const float* value = (const float*)d_in[2];
    const float* Wv    = (const float*)d_in[3];
    const float* bv    = (const float*)d_in[4];
    const float* Wl    = (const float*)d_in[5];
    const float* bl    = (const float*)d_in[6];
    const float* Wo    = (const float*)d_in[7];
    const float* bo    = (const float*)d_in[8];
    float* out = (float*)d_out;

    // B=2, L=2048, E=1024, M_land=64.
    // out = diag(1/rowsum(P)) * P * Ut^T + bo,  P = exp(ql kl^T / 8),
    // Ut = Wo @ Vproj^T (per batch),  Vproj = value @ Wv^T + bv.
    char* ws = (char*)d_ws;
    u16*   qkb    = (u16*)  (ws + 0);          // [8192,1024] bf16 (q rows, then k rows)
    u16*   vb     = (u16*)  (ws + 16777216);   // [2,2048,1024] bf16
    u16*   Wvb    = (u16*)  (ws + 25165824);   // [1024,1024]
    u16*   Wlb    = (u16*)  (ws + 27262976);   // [64,1024]
    u16*   Wob    = (u16*)  (ws + 27394048);   // [1024,1024]
    float* scores = (float*)(ws + 29491200);   // [8192,64] f32
    u16*   qlkl   = (u16*)  (ws + 31588352);   // [8192,64] bf16 (ql then kl)
    u16*   Vproj  = (u16*)  (ws + 32636928);   // [2,2048,1024] bf16
    u16*   Ut     = (u16*)  (ws + 41025536);   // [2,1024,2048] bf16
    u16*   Pm     = (u16*)  (ws + 49414144);   // [2,2048,2048] bf16
    float* rsc    = (float*)(ws + 66191360);   // [2,2048] f32 row sums of P

    // 1) casts fp32 -> bf16 (fused launches)
    cast_qkv<<<dim3(4096, 3), 256, 0, stream>>>(query, key, value,
                                                qkb, qkb + 4194304, vb, 4194304);
    cast_ww<<<dim3(1024, 2), 256, 0, stream>>>(Wv, Wo, Wvb, Wob, 1048576);
    cast_f2b_k<<<dim3(64), 256, 0, stream>>>(Wl, Wlb, 65536);

    // 2) landmark scores [8192,64] = qkb @ Wl^T ; then softmax over 64
    gemm_bt<32, 64, EPI_F32><<<dim3(1, 256, 1), 256, 0, stream>>>(
        qkb, Wlb, scores, 8192, 64, 1024, 0, 0, 0, nullptr, nullptr, 0.f);
    lm_softmax<<<dim3(2048), 256, 0, stream>>>(scores, bl, qlkl);

    // 3) Vproj[z] = value[z] @ Wv^T + bv  -> [2048,1024] bf16
    gemm_bt<64, 128, EPI_BF16_CB><<<dim3(8, 32, 2), 256, 0, stream>>>(
        vb, Wvb, Vproj, 2048, 1024, 1024, 2097152, 0, 2097152, bv, nullptr, 0.f);

    // 4) Ut[z] = Wo @ Vproj[z]^T  -> [1024,2048] bf16
    gemm_bt<128, 64, EPI_BF16><<<dim3(32, 8, 2), 256, 0, stream>>>(
        Wob, Vproj, Ut, 1024, 2048, 1024, 0, 2097152, 2097152, nullptr, nullptr, 0.f);

    // 5) P[z] = exp(ql kl^T / 8) bf16, with fused per-row sums (atomics)
    zero_f32<<<dim3(16), 256, 0, stream>>>(rsc, 4096);
    gemm_bt<128, 128, EPI_EXP_RS><<<dim3(16, 16, 2), 256, 0, stream>>>(
        qlkl, qlkl + 262144, Pm, 2048, 2048, 64,
        131072, 131072, 4194304, nullptr, rsc, 0.18033688011112042f);

    // 6) out[z] = diag(1/rsc) P[z] @ Ut[z]^T + bo  -> f32
    gemm_bt<64, 128, EPI_F32_DIV_CB><<<dim3(8, 32, 2), 256, 0, stream>>>(
        Pm, Ut, out, 2048, 1024, 2048,
        4194304, 2097152, 2097152, bo, rsc, 0.f);
}

// Round 3
// 201.548 us; speedup vs baseline: 1.2130x; 1.0258x over previous
//
#include <hip/hip_runtime.h>
#include <hip/hip_bf16.h>
#include <cstdint>

typedef unsigned short u16;
typedef __attribute__((ext_vector_type(8))) short short8;
typedef __attribute__((ext_vector_type(4))) float f32x4;
typedef __attribute__((ext_vector_type(4))) unsigned short us4;

__device__ __forceinline__ u16 f2bf(float f) {
    union { float f; unsigned int i; } v; v.f = f;
    unsigned int x = v.i;
    unsigned int r = x + 0x7fffu + ((x >> 16) & 1u);  // RNE
    return (u16)(r >> 16);
}

enum { EPI_F32 = 0, EPI_BF16 = 1, EPI_EXP_RS = 3, EPI_F32_DIV_CB = 4, EPI_LMSM = 5 };

// C[M,N] = A[M,K] * B[N,K]^T (both K-contiguous), batched via blockIdx.z.
// BK=64, 256 threads (4 waves 2x2), global_load_lds(16B) staging with XOR-8
// swizzle applied on the GLOBAL address side (LDS lane mapping is fixed:
// base + lane*16): chunk slot c_l of row r holds global chunk c_l^(r&7).
// Fragment reads invert the XOR -> bank-balanced ds_read_b128.
template <int BM, int BN, int EPI>
__global__ void __launch_bounds__(256)
gemm_bt(const u16* __restrict__ A, const u16* __restrict__ B, void* __restrict__ Cv,
        int M, int N, int K, long sA, long sB, long sC,
        const float* __restrict__ biasCol, float* __restrict__ rowScale, float expScale)
{
    constexpr int BK = 64;
    constexpr int MFRAG = (BM + 31) / 32;   // per-wave 16-row frags (wave covers BM/2)
    constexpr int NFRAG = BN / 32;
    __shared__ alignas(16) u16 As[BM * BK];
    __shared__ alignas(16) u16 Bs[BN * BK];

    const int tid = threadIdx.x;
    const int lane = tid & 63;
    const int quad = lane >> 4;
    const int l15 = lane & 15;
    const int w = tid >> 6;
    const int wm = w >> 1, wn = w & 1;
    const int z = blockIdx.z;
    const int m0 = blockIdx.y * BM;
    const int n0 = blockIdx.x * BN;

    const u16* Ab = A + (long)z * sA + (long)m0 * K;
    const u16* Bb = B + (long)z * sB + (long)n0 * K;

    const int r8 = tid >> 3;                    // 0..31 staging row within round
    const int cl = tid & 7;                     // LDS chunk slot (16B units)
    const int cg = ((cl ^ (r8 & 7)) * 8);       // swizzled global chunk (elements)

    const u16* ap[(BM + 31) / 32];
#pragma unroll
    for (int j = 0; j < (BM + 31) / 32; ++j) ap[j] = Ab + (long)(j * 32 + r8) * K + cg;
    const u16* bp[BN / 32];
#pragma unroll
    for (int j = 0; j < BN / 32; ++j) bp[j] = Bb + (long)(j * 32 + r8) * K + cg;

    f32x4 acc[MFRAG][NFRAG] = {};

    const int sw = l15 & 7;  // row XOR key for fragment reads

    for (int k0 = 0; k0 < K; k0 += BK) {
#pragma unroll
        for (int j = 0; j < (BM + 31) / 32; ++j) {
            __builtin_amdgcn_global_load_lds(
                (const __attribute__((address_space(1))) void*)(ap[j]),
                (__attribute__((address_space(3))) void*)(&As[(j * 32 + r8) * BK + cl * 8]),
                16, 0, 0);
            ap[j] += BK;
        }
#pragma unroll
        for (int j = 0; j < BN / 32; ++j) {
            __builtin_amdgcn_global_load_lds(
                (const __attribute__((address_space(1))) void*)(bp[j]),
                (__attribute__((address_space(3))) void*)(&Bs[(j * 32 + r8) * BK + cl * 8]),
                16, 0, 0);
            bp[j] += BK;
        }
        __syncthreads();
#pragma unroll
        for (int ks = 0; ks < 2; ++ks) {
            short8 af[MFRAG], bfr[NFRAG];
#pragma unroll
            for (int i = 0; i < MFRAG; ++i)
                af[i] = *(const short8*)&As[(wm * (BM / 2) + i * 16 + l15) * BK +
                                            (((ks * 4 + quad) ^ sw) * 8)];
#pragma unroll
            for (int i = 0; i < NFRAG; ++i)
                bfr[i] = *(const short8*)&Bs[(wn * (BN / 2) + i * 16 + l15) * BK +
                                             (((ks * 4 + quad) ^ sw) * 8)];
#pragma unroll
            for (int i = 0; i < MFRAG; ++i)
#pragma unroll
                for (int jn = 0; jn < NFRAG; ++jn)
                    acc[i][jn] = __builtin_amdgcn_mfma_f32_16x16x32_bf16(af[i], bfr[jn], acc[i][jn], 0, 0, 0);
        }
        __syncthreads();
    }

    // C/D layout: col=lane&15, row=quad*4+reg (m89/m91 verified).
    if constexpr (EPI == EPI_LMSM) {
        // BM=32, BN=64, grid.x==1: full softmax row inside the block.
        __shared__ float red[2][BM];
        float ev[4][NFRAG];
#pragma unroll
        for (int r = 0; r < 4; ++r) {
            float s = 0.f;
#pragma unroll
            for (int jn = 0; jn < NFRAG; ++jn) {
                const int col = wn * (BN / 2) + jn * 16 + l15;
                float v = exp2f((acc[0][jn][r] + biasCol[col]) * expScale);
                ev[r][jn] = v; s += v;
            }
            s += __shfl_xor(s, 1); s += __shfl_xor(s, 2);
            s += __shfl_xor(s, 4); s += __shfl_xor(s, 8);
            if (l15 == 0) red[wn][wm * 16 + quad * 4 + r] = s;
        }
        __syncthreads();
#pragma unroll
        for (int r = 0; r < 4; ++r) {
            const int mrow = wm * 16 + quad * 4 + r;
            const float inv = 1.0f / (red[0][mrow] + red[1][mrow]);
            const long m = m0 + mrow;
#pragma unroll
            for (int jn = 0; jn < NFRAG; ++jn) {
                const int col = wn * (BN / 2) + jn * 16 + l15;
                ((u16*)Cv)[m * N + col] = f2bf(ev[r][jn] * inv);
            }
        }
        return;
    } else {
#pragma unroll
        for (int i = 0; i < MFRAG; ++i) {
            const int mb = m0 + wm * (BM / 2) + i * 16 + quad * 4;
#pragma unroll
            for (int r = 0; r < 4; ++r) {
                const int m = mb + r;
                float rin = 0.f;
                if constexpr (EPI == EPI_F32_DIV_CB) rin = 1.0f / rowScale[(long)z * M + m];
                float rowsum = 0.f;
#pragma unroll
                for (int jn = 0; jn < NFRAG; ++jn) {
                    const int col = n0 + wn * (BN / 2) + jn * 16 + l15;
                    float v = acc[i][jn][r];
                    if constexpr (EPI == EPI_EXP_RS) { v = exp2f(v * expScale); rowsum += v; }
                    if constexpr (EPI == EPI_F32_DIV_CB) v = v * rin + biasCol[col];
                    if constexpr (EPI == EPI_F32 || EPI == EPI_F32_DIV_CB)
                        ((float*)Cv)[(long)z * sC + (long)m * N + col] = v;
                    else
                        ((u16*)Cv)[(long)z * sC + (long)m * N + col] = f2bf(v);
                }
                if constexpr (EPI == EPI_EXP_RS) {
                    rowsum += __shfl_xor(rowsum, 1);
                    rowsum += __shfl_xor(rowsum, 2);
                    rowsum += __shfl_xor(rowsum, 4);
                    rowsum += __shfl_xor(rowsum, 8);
                    if (l15 == 0) atomicAdd(&rowScale[(long)z * M + m], rowsum);
                }
            }
        }
    }
}

// q,k,v fp32 -> bf16 (grid.y selects tensor)
__global__ void __launch_bounds__(256)
cast_qkv(const float* __restrict__ a, const float* __restrict__ b, const float* __restrict__ c,
         u16* __restrict__ oa, u16* __restrict__ ob, u16* __restrict__ oc, long n)
{
    const float* s; u16* d;
    if (blockIdx.y == 0)      { s = a; d = oa; }
    else if (blockIdx.y == 1) { s = b; d = ob; }
    else                      { s = c; d = oc; }
    long i = ((long)blockIdx.x * 256 + threadIdx.x) * 4;
    if (i < n) {
        const float4 v = *(const float4*)(s + i);
        us4 o;
        o.x = f2bf(v.x); o.y = f2bf(v.y); o.z = f2bf(v.z); o.w = f2bf(v.w);
        *(us4*)(d + i) = o;
    }
}

// Wo (1M elems) then Wl (64K elems) in one launch: grid 1088 blocks
__global__ void __launch_bounds__(256)
cast_wowl(const float* __restrict__ wo, const float* __restrict__ wl,
          u16* __restrict__ owo, u16* __restrict__ owl)
{
    long i = ((long)blockIdx.x * 256 + threadIdx.x) * 4;
    const float* s; u16* d;
    if (i < 1048576) { s = wo; d = owo; }
    else { i -= 1048576; s = wl; d = owl; }
    const float4 v = *(const float4*)(s + i);
    us4 o;
    o.x = f2bf(v.x); o.y = f2bf(v.y); o.z = f2bf(v.z); o.w = f2bf(v.w);
    *(us4*)(d + i) = o;
}

// WvT[e,d] = bf16(Wv[d,e]) via padded LDS tile; also zeroes rsc (4096 f32).
__global__ void __launch_bounds__(256)
castT_wv(const float* __restrict__ src, u16* __restrict__ dst, float* __restrict__ rsc)
{
    __shared__ float t[64][65];
    const int bx = blockIdx.x, by = blockIdx.y;
    const int tid = threadIdx.x;
#pragma unroll
    for (int p = 0; p < 16; ++p) {
        int idx = p * 256 + tid;
        int r = idx >> 6, c = idx & 63;
        t[r][c] = src[(long)(by * 64 + r) * 1024 + bx * 64 + c];
    }
    __syncthreads();
#pragma unroll
    for (int p = 0; p < 16; ++p) {
        int idx = p * 256 + tid;
        int c = idx >> 6, r = idx & 63;
        dst[(long)(bx * 64 + c) * 1024 + by * 64 + r] = f2bf(t[r][c]);
    }
    if (bx == 0 && by < 16) rsc[by * 256 + tid] = 0.f;
}

// bocomb = bo + Wo @ bv  (one wave per row)
__global__ void __launch_bounds__(256)
bias_comb(const float* __restrict__ Wo, const float* __restrict__ bv,
          const float* __restrict__ bo, float* __restrict__ out)
{
    int row = blockIdx.x * 4 + (threadIdx.x >> 6);
    int lane = threadIdx.x & 63;
    float s = 0.f;
#pragma unroll
    for (int i = 0; i < 16; ++i) s += Wo[(long)row * 1024 + i * 64 + lane] * bv[i * 64 + lane];
    for (int o = 32; o; o >>= 1) s += __shfl_xor(s, o, 64);
    if (lane == 0) out[row] = bo[row] + s;
}

extern "C" void kernel_launch(void* const* d_in, const int* in_sizes, int n_in,
                              void* d_out, int out_size, void* d_ws, size_t ws_size,
                              hipStream_t stream)
{
    const float* query = (const float*)d_in[0];
    const float* key   = (const float*)d_in[1];
    const float* value = (const float*)d_in[2];
    const float* Wv    = (const float*)d_in[3];
    const float* bv    = (const float*)d_in[4];
    const float* Wl    = (const float*)d_in[5];
    const float* bl    = (const float*)d_in[6];
    const float* Wo    = (const float*)d_in[7];
    const float* bo    = (const float*)d_in[8];
    float* out = (float*)d_out;

    // B=2, L=2048, E=1024, M_land=64.
    // out = diag(1/rowsum(P)) P value Wov^T + 1*(Wo bv + bo)^T,
    //   P = exp(ql kl^T / 8),  Wov = Wo @ Wv,  Ut = Wov @ value^T.
    char* ws = (char*)d_ws;
    u16*   qkb    = (u16*)  (ws + 0);          // [8192,1024] (q rows then k rows)
    u16*   vb     = (u16*)  (ws + 16777216);   // [2,2048,1024]
    u16*   Wlb    = (u16*)  (ws + 25165824);   // [64,1024]
    u16*   Wob    = (u16*)  (ws + 25296896);   // [1024,1024]
    u16*   WvT    = (u16*)  (ws + 27394048);   // [1024(e),1024(d)]
    u16*   Wov    = (u16*)  (ws + 29491200);   // [1024(o),1024(e)]
    u16*   qlkl   = (u16*)  (ws + 31588352);   // [8192,64] (ql then kl)
    u16*   Ut     = (u16*)  (ws + 32636928);   // [2,1024(o),2048(k)]
    u16*   Pm     = (u16*)  (ws + 41025536);   // [2,2048,2048]
    float* rsc    = (float*)(ws + 57802752);   // [2,2048] row sums of P
    float* bocomb = (float*)(ws + 57819136);   // [1024]

    // 1) casts
    cast_qkv<<<dim3(4096, 3), 256, 0, stream>>>(query, key, value,
                                                qkb, qkb + 4194304, vb, 4194304);
    cast_wowl<<<dim3(1088), 256, 0, stream>>>(Wo, Wl, Wob, Wlb);
    castT_wv<<<dim3(16, 16), 256, 0, stream>>>(Wv, WvT, rsc);
    bias_comb<<<dim3(256), 256, 0, stream>>>(Wo, bv, bo, bocomb);

    // 2) ql/kl = softmax((qk @ Wl^T + bl)/8), fused epilogue softmax
    gemm_bt<32, 64, EPI_LMSM><<<dim3(1, 256, 1), 256, 0, stream>>>(
        qkb, Wlb, qlkl, 8192, 64, 1024, 0, 0, 0, bl, nullptr, 0.18033688011112042f);

    // 3) Wov = Wo @ Wv  -> [1024,1024] bf16
    gemm_bt<64, 64, EPI_BF16><<<dim3(16, 16, 1), 256, 0, stream>>>(
        Wob, WvT, Wov, 1024, 1024, 1024, 0, 0, 0, nullptr, nullptr, 0.f);

    // 4) Ut[z] = Wov @ value[z]^T -> [1024,2048] bf16
    gemm_bt<128, 64, EPI_BF16><<<dim3(32, 8, 2), 256, 0, stream>>>(
        Wov, vb, Ut, 1024, 2048, 1024, 0, 2097152, 2097152, nullptr, nullptr, 0.f);

    // 5) P[z] = exp(ql kl^T / 8) bf16, fused per-row sums (atomics into rsc)
    gemm_bt<128, 128, EPI_EXP_RS><<<dim3(16, 16, 2), 256, 0, stream>>>(
        qlkl, qlkl + 262144, Pm, 2048, 2048, 64,
        131072, 131072, 4194304, nullptr, rsc, 0.18033688011112042f);

    // 6) out[z] = diag(1/rsc) P[z] @ Ut[z]^T + bocomb -> f32
    gemm_bt<64, 128, EPI_F32_DIV_CB><<<dim3(8, 32, 2), 256, 0, stream>>>(
        Pm, Ut, out, 2048, 1024, 2048,
        4194304, 2097152, 2097152, bocomb, rsc, 0.f);
}